// Round 4
// baseline (3321.838 us; speedup 1.0000x reference)
//
#include <hip/hip_runtime.h>

// VQ-VAE quantize: z [32,64,64,64] NCHW fp32, codebook [512,64] fp32.
// out = quantized [32,64,64,64] NCHW (8388608 floats) ++ loss scalar (1 float).
// N = 131072 positions, D = 64, K = 512.
//
// R4: cooperative register-tiled GEMM. R1-R3 proved the allocator will not
// keep a per-thread float[64] in VGPRs (VGPR_Count pinned at 52; scratch
// re-reads every k-tile). New structure: block = 64 positions x 512 codes;
// zS (transposed) + codebook K-tiles (transposed) in LDS; each thread owns a
// 4-pos x 8-code acc tile (32 VGPRs, constant-indexed -> register-resident).
// Dot = sequential-d fp32 FMA chain; dist = (znorm - 2*dot) + cnorm, same
// association as the numpy reference (absmax 0.0 in R1-R3 validates this).

#define Bz   32
#define Dz   64
#define HWz  4096
#define Nz   (Bz * HWz)         // 131072
#define Kz   512
#define QSIZE ((size_t)Nz * Dz) // 8388608
#define KT   128                // codes per K-tile
#define TS   68                 // zS row stride (floats), 16B-aligned, padded
#define CS   132                // cT row stride (floats), 16B-aligned, padded

__global__ __launch_bounds__(256, 2) void vq_main(
    const float* __restrict__ z, const float* __restrict__ cb,
    float* __restrict__ out, float* __restrict__ loss_accum,
    unsigned int* __restrict__ done_counter) {
    __shared__ float zS[64 * TS];      // zS[p*TS + d]
    __shared__ float cT[Dz * CS];      // cT[d*CS + kt], kt in [0,KT)
    __shared__ float cnormS[Kz];
    __shared__ int   idxS[64];
    __shared__ float wsum[4];

    const int t  = threadIdx.x;
    const int tp = t >> 4;             // 0..15 -> positions 4tp..4tp+3
    const int tk = t & 15;             // 0..15 -> codes 8tk..8tk+7 (per tile)
    const int n0 = blockIdx.x * 64;
    const int b  = n0 >> 12;
    const int s0 = n0 & 4095;
    const float* zbase = z + (size_t)b * (Dz * HWz) + s0;

    // ---- Stage zS (transpose): zS[p][d] = z[d][s0+p]. Coalesced 256B rows.
    {
        const int i = 4 * tk;
#pragma unroll
        for (int pass = 0; pass < 4; ++pass) {
            const int d = tp + 16 * pass;
            float4 f = *(const float4*)(zbase + (size_t)d * HWz + i);
            zS[(i + 0) * TS + d] = f.x;
            zS[(i + 1) * TS + d] = f.y;
            zS[(i + 2) * TS + d] = f.z;
            zS[(i + 3) * TS + d] = f.w;
        }
    }

    // ---- cnorm for all 512 codes, numpy pairwise-exact (squares round
    // before add -> contraction off).
    {
#pragma clang fp contract(off)
#pragma unroll
        for (int h = 0; h < 2; ++h) {
            const int k = t + 256 * h;
            const float4* row = (const float4*)(cb + (size_t)k * 64);
            float r0, r1, r2, r3, r4, r5, r6, r7;
            {
                float4 f0 = row[0], f1 = row[1];
                r0 = f0.x * f0.x; r1 = f0.y * f0.y; r2 = f0.z * f0.z; r3 = f0.w * f0.w;
                r4 = f1.x * f1.x; r5 = f1.y * f1.y; r6 = f1.z * f1.z; r7 = f1.w * f1.w;
            }
#pragma unroll
            for (int m = 1; m < 8; ++m) {
                float4 f0 = row[2 * m], f1 = row[2 * m + 1];
                r0 = r0 + f0.x * f0.x; r1 = r1 + f0.y * f0.y;
                r2 = r2 + f0.z * f0.z; r3 = r3 + f0.w * f0.w;
                r4 = r4 + f1.x * f1.x; r5 = r5 + f1.y * f1.y;
                r6 = r6 + f1.z * f1.z; r7 = r7 + f1.w * f1.w;
            }
            cnormS[k] = ((r0 + r1) + (r2 + r3)) + ((r4 + r5) + (r6 + r7));
        }
    }
    __syncthreads();

    // ---- znorm for this thread's 4 positions (numpy pairwise-exact).
    float zn[4];
    {
#pragma clang fp contract(off)
#pragma unroll
        for (int pp = 0; pp < 4; ++pp) {
            const float4* rowz = (const float4*)(zS + (4 * tp + pp) * TS);
            float r0, r1, r2, r3, r4, r5, r6, r7;
            {
                float4 f0 = rowz[0], f1 = rowz[1];
                r0 = f0.x * f0.x; r1 = f0.y * f0.y; r2 = f0.z * f0.z; r3 = f0.w * f0.w;
                r4 = f1.x * f1.x; r5 = f1.y * f1.y; r6 = f1.z * f1.z; r7 = f1.w * f1.w;
            }
#pragma unroll
            for (int m = 1; m < 8; ++m) {
                float4 f0 = rowz[2 * m], f1 = rowz[2 * m + 1];
                r0 = r0 + f0.x * f0.x; r1 = r1 + f0.y * f0.y;
                r2 = r2 + f0.z * f0.z; r3 = r3 + f0.w * f0.w;
                r4 = r4 + f1.x * f1.x; r5 = r5 + f1.y * f1.y;
                r6 = r6 + f1.z * f1.z; r7 = r7 + f1.w * f1.w;
            }
            zn[pp] = ((r0 + r1) + (r2 + r3)) + ((r4 + r5) + (r6 + r7));
        }
    }

    // ---- K loop over 4 tiles of 128 codes.
    float rb_d[4]; int rb_k[4];
#pragma unroll
    for (int pp = 0; pp < 4; ++pp) { rb_d[pp] = __builtin_inff(); rb_k[pp] = 0; }

    for (int k0 = 0; k0 < Kz; k0 += KT) {
        __syncthreads();  // previous tile's reads complete before overwrite
        // Stage cT (transpose): cT[d][kt] = cb[k0+kt][d]. LDS writes are
        // conflict-free: bank = (t&15) + 16*((t>>4)&1) + 4j covers all 32.
#pragma unroll
        for (int pass = 0; pass < 8; ++pass) {
            const int kt = (t & 15) + 16 * pass;
            const int d0 = 4 * (t >> 4);
            float4 f = *(const float4*)(cb + (size_t)(k0 + kt) * 64 + d0);
            cT[(d0 + 0) * CS + kt] = f.x;
            cT[(d0 + 1) * CS + kt] = f.y;
            cT[(d0 + 2) * CS + kt] = f.z;
            cT[(d0 + 3) * CS + kt] = f.w;
        }
        __syncthreads();

        float acc[4][8];
#pragma unroll
        for (int pp = 0; pp < 4; ++pp)
#pragma unroll
            for (int kk = 0; kk < 8; ++kk) acc[pp][kk] = 0.f;

#pragma unroll
        for (int dc = 0; dc < 16; ++dc) {
            const int d0 = 4 * dc;
            float4 zf[4];
#pragma unroll
            for (int pp = 0; pp < 4; ++pp)
                zf[pp] = *(const float4*)(zS + (4 * tp + pp) * TS + d0);
#pragma unroll
            for (int dd = 0; dd < 4; ++dd) {   // d ascending -> exact chain
                const float4 c0 = *(const float4*)(cT + (d0 + dd) * CS + 8 * tk);
                const float4 c1 = *(const float4*)(cT + (d0 + dd) * CS + 8 * tk + 4);
#pragma unroll
                for (int pp = 0; pp < 4; ++pp) {
                    const float zd = ((const float*)&zf[pp])[dd];
                    acc[pp][0] = __builtin_fmaf(zd, c0.x, acc[pp][0]);
                    acc[pp][1] = __builtin_fmaf(zd, c0.y, acc[pp][1]);
                    acc[pp][2] = __builtin_fmaf(zd, c0.z, acc[pp][2]);
                    acc[pp][3] = __builtin_fmaf(zd, c0.w, acc[pp][3]);
                    acc[pp][4] = __builtin_fmaf(zd, c1.x, acc[pp][4]);
                    acc[pp][5] = __builtin_fmaf(zd, c1.y, acc[pp][5]);
                    acc[pp][6] = __builtin_fmaf(zd, c1.z, acc[pp][6]);
                    acc[pp][7] = __builtin_fmaf(zd, c1.w, acc[pp][7]);
                }
            }
        }

        // Distances + argmin. Local scan kk ascending (strict < = first-win),
        // then 16-lane butterfly with lower-k tie-break, then running merge.
#pragma unroll
        for (int pp = 0; pp < 4; ++pp) {
            float bd = __builtin_inff(); int bk = 0;
#pragma unroll
            for (int kk = 0; kk < 8; ++kk) {
                const int k = k0 + 8 * tk + kk;
                const float dist = (zn[pp] - 2.0f * acc[pp][kk]) + cnormS[k];
                if (dist < bd) { bd = dist; bk = k; }
            }
#pragma unroll
            for (int m = 1; m < 16; m <<= 1) {
                const float od = __shfl_xor(bd, m, 64);
                const int   ok = __shfl_xor(bk, m, 64);
                if (od < bd || (od == bd && ok < bk)) { bd = od; bk = ok; }
            }
            if (tk == 0 && bd < rb_d[pp]) { rb_d[pp] = bd; rb_k[pp] = bk; }
        }
    }

    if (tk == 0) {
#pragma unroll
        for (int pp = 0; pp < 4; ++pp) idxS[4 * tp + pp] = rb_k[pp];
    }
    __syncthreads();

    // ---- Epilogue: gather chosen code, write q_st (NCHW, coalesced), loss.
    const int p  = t & 63;
    const int dg = t >> 6;   // 0..3 -> d range 16*dg..16*dg+15
    const int myidx = idxS[p];
    const float* qrow = cb + (size_t)myidx * 64 + 16 * dg;
    float* obase = out + (size_t)b * (Dz * HWz) + s0 + p;
    float lsum = 0.f;
#pragma unroll
    for (int j = 0; j < 4; ++j) {
        const int d = 16 * dg + 4 * j;
        const float4 q4 = *(const float4*)(qrow + 4 * j);
        const float4 z4 = *(const float4*)(zS + p * TS + d);
        const float e0 = z4.x - q4.x, e1 = z4.y - q4.y;
        const float e2 = z4.z - q4.z, e3 = z4.w - q4.w;
        lsum += e0 * e0 + e1 * e1 + e2 * e2 + e3 * e3;
        obase[(size_t)(d + 0) * HWz] = z4.x + (q4.x - z4.x);
        obase[(size_t)(d + 1) * HWz] = z4.y + (q4.y - z4.y);
        obase[(size_t)(d + 2) * HWz] = z4.z + (q4.z - z4.z);
        obase[(size_t)(d + 3) * HWz] = z4.w + (q4.w - z4.w);
    }

    // ---- Loss reduction: wave shuffle -> LDS -> one atomic -> ticket.
#pragma unroll
    for (int off = 32; off > 0; off >>= 1) lsum += __shfl_down(lsum, off, 64);
    const int lane = t & 63, wid = t >> 6;
    if (lane == 0) wsum[wid] = lsum;
    __syncthreads();
    if (t == 0) {
        float tot = (wsum[0] + wsum[1]) + (wsum[2] + wsum[3]);
        atomicAdd(loss_accum, tot);
        __threadfence();
        unsigned int ticket = atomicAdd(done_counter, 1u);
        if (ticket == gridDim.x - 1) {
            __threadfence();
            float total = atomicAdd(loss_accum, 0.0f);
            float X = total / (float)QSIZE;
            out[QSIZE] = X + 0.25f * X;
        }
    }
}

extern "C" void kernel_launch(void* const* d_in, const int* in_sizes, int n_in,
                              void* d_out, int out_size, void* d_ws, size_t ws_size,
                              hipStream_t stream) {
    const float* z  = (const float*)d_in[0];
    const float* cb = (const float*)d_in[1];
    float* out = (float*)d_out;
    float* wsf = (float*)d_ws;
    hipMemsetAsync(d_ws, 0, 8, stream);
    vq_main<<<Nz / 64, 256, 0, stream>>>(z, cb, out, wsf, (unsigned int*)(wsf + 1));
}

// Round 5
// 305.831 us; speedup vs baseline: 10.8617x; 10.8617x over previous
//
#include <hip/hip_runtime.h>

// VQ-VAE quantize: z [32,64,64,64] NCHW fp32, codebook [512,64] fp32.
// out = quantized [32,64,64,64] NCHW (8388608 floats) ++ loss scalar (1 float).
// N = 131072 positions, D = 64, K = 512.
//
// R5: z lives in LDS d-major (zT[d][p], lane=position -> conflict-free b32),
// codebook stays wave-uniform -> s_load -> SGPR operand of v_fmac_f32.
// Thread = 1 position x 16 concurrent codes in 16 NAMED scalar accumulators
// (R4 post-mortem: address-taken register arrays fell to scratch -> 10 GB of
// HBM thrash). Per 4-d chunk: 4 ds_read_b32 feed 64 FMAs -> VALU-bound 1.4x.
// Argmin is thread-local (k ascending, strict <). Same bit-exact arithmetic
// as R1 (absmax 0.0): sequential-d FMA dot, pairwise-8 norms, (zn-2a)+cn.

#define Bz   32
#define Dz   64
#define HWz  4096
#define Nz   (Bz * HWz)         // 131072
#define Kz   512
#define QSIZE ((size_t)Nz * Dz) // 8388608

#define FMA4(c)                                                         \
    {                                                                   \
        const float4 C = *(const float4*)(cbk + (c) * 64 + d0);         \
        a##c = __builtin_fmaf(z0, C.x, a##c);                           \
        a##c = __builtin_fmaf(z1, C.y, a##c);                           \
        a##c = __builtin_fmaf(z2, C.z, a##c);                           \
        a##c = __builtin_fmaf(z3, C.w, a##c);                           \
    }

#define UPD(c)                                                          \
    {                                                                   \
        const float dist = (zn - 2.0f * a##c) + cnormS[k0 + (c)];       \
        if (dist < bd) { bd = dist; bk = k0 + (c); }                    \
    }

__global__ __launch_bounds__(256, 2) void vq_main(
    const float* __restrict__ z, const float* __restrict__ cb,
    float* __restrict__ out, float* __restrict__ loss_accum,
    unsigned int* __restrict__ done_counter) {
    __shared__ float zT[Dz * 256];   // zT[d*256 + p], d-major
    __shared__ float cnormS[Kz];
    __shared__ float wsum[4];

    const int t  = threadIdx.x;
    const int w  = t >> 6;           // wave id 0..3
    const int l  = t & 63;           // lane
    const int n0 = blockIdx.x * 256;
    const int b  = n0 >> 12;
    const int s0 = n0 & 4095;
    const float* zB = z + (size_t)b * (Dz * HWz);

    // ---- Stage zT: wave w loads rows d = 4i+w; lanes cover 256 consecutive
    // floats (1 KB/inst, fully coalesced). LDS b128 write conflicts are cheap
    // here (one-time staging).
#pragma unroll
    for (int i = 0; i < 16; ++i) {
        const int d = 4 * i + w;
        float4 f = *(const float4*)(zB + (size_t)d * HWz + s0 + 4 * l);
        *(float4*)(zT + d * 256 + 4 * l) = f;
    }

    // ---- cnorm for all 512 codes (numpy pairwise-8 exact; squares round
    // before add -> contraction off). 2 rows per thread.
    {
#pragma clang fp contract(off)
#pragma unroll
        for (int h = 0; h < 2; ++h) {
            const int k = t + 256 * h;
            const float4* row = (const float4*)(cb + (size_t)k * 64);
            float r0, r1, r2, r3, r4, r5, r6, r7;
            {
                float4 f0 = row[0], f1 = row[1];
                r0 = f0.x * f0.x; r1 = f0.y * f0.y; r2 = f0.z * f0.z; r3 = f0.w * f0.w;
                r4 = f1.x * f1.x; r5 = f1.y * f1.y; r6 = f1.z * f1.z; r7 = f1.w * f1.w;
            }
#pragma unroll
            for (int m = 1; m < 8; ++m) {
                float4 f0 = row[2 * m], f1 = row[2 * m + 1];
                r0 = r0 + f0.x * f0.x; r1 = r1 + f0.y * f0.y;
                r2 = r2 + f0.z * f0.z; r3 = r3 + f0.w * f0.w;
                r4 = r4 + f1.x * f1.x; r5 = r5 + f1.y * f1.y;
                r6 = r6 + f1.z * f1.z; r7 = r7 + f1.w * f1.w;
            }
            cnormS[k] = ((r0 + r1) + (r2 + r3)) + ((r4 + r5) + (r6 + r7));
        }
    }
    __syncthreads();

    // ---- znorm for this thread's position (pairwise-8 exact, from LDS).
    float zn;
    {
#pragma clang fp contract(off)
        float r0, r1, r2, r3, r4, r5, r6, r7;
        {
            float v0 = zT[0 * 256 + t], v1 = zT[1 * 256 + t];
            float v2 = zT[2 * 256 + t], v3 = zT[3 * 256 + t];
            float v4 = zT[4 * 256 + t], v5 = zT[5 * 256 + t];
            float v6 = zT[6 * 256 + t], v7 = zT[7 * 256 + t];
            r0 = v0 * v0; r1 = v1 * v1; r2 = v2 * v2; r3 = v3 * v3;
            r4 = v4 * v4; r5 = v5 * v5; r6 = v6 * v6; r7 = v7 * v7;
        }
#pragma unroll
        for (int m = 1; m < 8; ++m) {
            float v0 = zT[(8 * m + 0) * 256 + t], v1 = zT[(8 * m + 1) * 256 + t];
            float v2 = zT[(8 * m + 2) * 256 + t], v3 = zT[(8 * m + 3) * 256 + t];
            float v4 = zT[(8 * m + 4) * 256 + t], v5 = zT[(8 * m + 5) * 256 + t];
            float v6 = zT[(8 * m + 6) * 256 + t], v7 = zT[(8 * m + 7) * 256 + t];
            r0 = r0 + v0 * v0; r1 = r1 + v1 * v1; r2 = r2 + v2 * v2; r3 = r3 + v3 * v3;
            r4 = r4 + v4 * v4; r5 = r5 + v5 * v5; r6 = r6 + v6 * v6; r7 = r7 + v7 * v7;
        }
        zn = ((r0 + r1) + (r2 + r3)) + ((r4 + r5) + (r6 + r7));
    }

    // ---- K loop: 32 groups of 16 codes. No barriers, no shuffles.
    float bd = __builtin_inff();
    int   bk = 0;
#pragma unroll 1
    for (int k0 = 0; k0 < Kz; k0 += 16) {
        const float* cbk = cb + (size_t)k0 * 64;   // wave-uniform -> s_load
        float a0 = 0.f, a1 = 0.f, a2 = 0.f, a3 = 0.f;
        float a4 = 0.f, a5 = 0.f, a6 = 0.f, a7 = 0.f;
        float a8 = 0.f, a9 = 0.f, a10 = 0.f, a11 = 0.f;
        float a12 = 0.f, a13 = 0.f, a14 = 0.f, a15 = 0.f;
#pragma unroll 2
        for (int d0 = 0; d0 < 64; d0 += 4) {
            const float z0 = zT[(d0 + 0) * 256 + t];
            const float z1 = zT[(d0 + 1) * 256 + t];
            const float z2 = zT[(d0 + 2) * 256 + t];
            const float z3 = zT[(d0 + 3) * 256 + t];
            FMA4(0)  FMA4(1)  FMA4(2)  FMA4(3)
            FMA4(4)  FMA4(5)  FMA4(6)  FMA4(7)
            FMA4(8)  FMA4(9)  FMA4(10) FMA4(11)
            FMA4(12) FMA4(13) FMA4(14) FMA4(15)
        }
        UPD(0)  UPD(1)  UPD(2)  UPD(3)
        UPD(4)  UPD(5)  UPD(6)  UPD(7)
        UPD(8)  UPD(9)  UPD(10) UPD(11)
        UPD(12) UPD(13) UPD(14) UPD(15)
    }

    // ---- Epilogue: gather chosen code, write q_st (NCHW coalesced), loss.
    const float* q = cb + (size_t)bk * 64;
    float* oB = out + (size_t)b * (Dz * HWz) + s0 + t;
    float lsum = 0.f;
#pragma unroll
    for (int d0 = 0; d0 < 64; d0 += 4) {
        const float4 q4 = *(const float4*)(q + d0);
        const float z0 = zT[(d0 + 0) * 256 + t];
        const float z1 = zT[(d0 + 1) * 256 + t];
        const float z2 = zT[(d0 + 2) * 256 + t];
        const float z3 = zT[(d0 + 3) * 256 + t];
        const float e0 = z0 - q4.x, e1 = z1 - q4.y;
        const float e2 = z2 - q4.z, e3 = z3 - q4.w;
        lsum += e0 * e0; lsum += e1 * e1; lsum += e2 * e2; lsum += e3 * e3;
        oB[(size_t)(d0 + 0) * HWz] = z0 + (q4.x - z0);
        oB[(size_t)(d0 + 1) * HWz] = z1 + (q4.y - z1);
        oB[(size_t)(d0 + 2) * HWz] = z2 + (q4.z - z2);
        oB[(size_t)(d0 + 3) * HWz] = z3 + (q4.w - z3);
    }

    // ---- Loss reduction: wave shuffle -> LDS -> one atomic -> ticket.
#pragma unroll
    for (int off = 32; off > 0; off >>= 1) lsum += __shfl_down(lsum, off, 64);
    if (l == 0) wsum[w] = lsum;
    __syncthreads();
    if (t == 0) {
        float tot = (wsum[0] + wsum[1]) + (wsum[2] + wsum[3]);
        atomicAdd(loss_accum, tot);
        __threadfence();
        unsigned int ticket = atomicAdd(done_counter, 1u);
        if (ticket == gridDim.x - 1) {
            __threadfence();
            float total = atomicAdd(loss_accum, 0.0f);
            float X = total / (float)QSIZE;
            out[QSIZE] = X + 0.25f * X;
        }
    }
}

extern "C" void kernel_launch(void* const* d_in, const int* in_sizes, int n_in,
                              void* d_out, int out_size, void* d_ws, size_t ws_size,
                              hipStream_t stream) {
    const float* z  = (const float*)d_in[0];
    const float* cb = (const float*)d_in[1];
    float* out = (float*)d_out;
    float* wsf = (float*)d_ws;
    hipMemsetAsync(d_ws, 0, 8, stream);
    vq_main<<<Nz / 256, 256, 0, stream>>>(z, cb, out, wsf, (unsigned int*)(wsf + 1));
}